// Round 8
// baseline (5367.662 us; speedup 1.0000x reference)
//
#include <hip/hip_runtime.h>
#include <math.h>

#define NV 500
#define NB 32
#define NT 24
#define NH 64

typedef _Float16 f16;
typedef _Float16 f16x8 __attribute__((ext_vector_type(8)));
typedef _Float16 f16x4 __attribute__((ext_vector_type(4)));
typedef float    f32x4 __attribute__((ext_vector_type(4)));

__device__ __forceinline__ float sigm(float x){ return 1.f/(1.f+expf(-x)); }

// ======================= prep: A transpose/cast + A^2 via MFMA (R7-verified) =======================
__global__ __launch_bounds__(256)
void k_prep_a(const float* __restrict__ A, f16* __restrict__ AcatT, f16* __restrict__ A16)
{
    __shared__ float t[64][65];
    const int s = blockIdx.z;
    const int v0 = blockIdx.y*64, w0 = blockIdx.x*64;
    const float* As = A + (size_t)s*500*500;
    const int tid = threadIdx.x;
    for (int e = tid; e < 64*64; e += 256) {
        int r = e>>6, c = e&63;
        int v = v0+r, w = w0+c;
        float val = (v < 500 && w < 500) ? As[(size_t)v*500 + w] : 0.f;
        t[r][c] = val;
        A16[((size_t)s*512 + v)*512 + w] = (f16)val;
    }
    __syncthreads();
    for (int e = tid; e < 64*64; e += 256) {
        int wr = e>>6, vc = e&63;
        AcatT[((size_t)(2*s)*512 + w0+wr)*512 + v0+vc] = (f16)t[vc][wr];
    }
}

__global__ __launch_bounds__(256)
void k_a2m(f16* __restrict__ AcatT, const f16* __restrict__ A16)
{
    __shared__ f16 lA[128*32];
    __shared__ f16 lB[128*32];
    const int tid = threadIdx.x;
    const int s = blockIdx.z;
    const int n0 = blockIdx.x*128, m0 = blockIdx.y*128;
    const f16* AT = AcatT + (size_t)(2*s)*512*512;
    const f16* Y  = A16 + (size_t)s*512*512;
    f16* D = AcatT + (size_t)(2*s+1)*512*512;

    const int r0 = tid>>2, c0 = tid&3;
    const int swz0 = r0*32 + ((c0 ^ ((r0>>1)&3))<<3);
    const int swz1 = swz0 + 64*32;
    const f16* gA0 = AT + (size_t)(m0+r0)*512 + c0*8;
    const f16* gA1 = AT + (size_t)(m0+r0+64)*512 + c0*8;
    const f16* gB0 = Y + (size_t)(n0+r0)*512 + c0*8;
    const f16* gB1 = Y + (size_t)(n0+r0+64)*512 + c0*8;

    const int w = tid>>6, lane = tid&63;
    const int wr = (w>>1)<<6, wc = (w&1)<<6;
    const int fm = lane&15, fk = lane>>4;
    const int fch = (fk ^ ((fm>>1)&3))<<3;

    f32x4 acc[4][4];
    #pragma unroll
    for (int i=0;i<4;i++)
        #pragma unroll
        for (int j=0;j<4;j++) acc[i][j] = (f32x4){0.f,0.f,0.f,0.f};

    f32x4 ra0 = *(const f32x4*)gA0, ra1 = *(const f32x4*)gA1;
    f32x4 rb0 = *(const f32x4*)gB0, rb1 = *(const f32x4*)gB1;

    for (int ks = 0; ks < 16; ks++) {
        __syncthreads();
        *(f32x4*)(lA + swz0) = ra0;  *(f32x4*)(lA + swz1) = ra1;
        *(f32x4*)(lB + swz0) = rb0;  *(f32x4*)(lB + swz1) = rb1;
        if (ks < 15) {
            int o = (ks+1)*32;
            ra0 = *(const f32x4*)(gA0 + o); ra1 = *(const f32x4*)(gA1 + o);
            rb0 = *(const f32x4*)(gB0 + o); rb1 = *(const f32x4*)(gB1 + o);
        }
        __syncthreads();
        f16x8 af[4], bf[4];
        #pragma unroll
        for (int i=0;i<4;i++) af[i] = *(const f16x8*)(lA + (wr + i*16 + fm)*32 + fch);
        #pragma unroll
        for (int j=0;j<4;j++) bf[j] = *(const f16x8*)(lB + (wc + j*16 + fm)*32 + fch);
        #pragma unroll
        for (int i=0;i<4;i++)
            #pragma unroll
            for (int j=0;j<4;j++)
                acc[i][j] = __builtin_amdgcn_mfma_f32_16x16x32_f16(af[i], bf[j], acc[i][j], 0, 0, 0);
    }

    #pragma unroll
    for (int j=0;j<4;j++) {
        int col = n0 + wc + j*16 + fm;
        #pragma unroll
        for (int i=0;i<4;i++) {
            int mb = m0 + wr + i*16 + fk*4;
            #pragma unroll
            for (int r=0;r<4;r++)
                D[(size_t)(mb+r)*512 + col] = (f16)acc[i][j][r];
        }
    }
}

__global__ void k_f2h(const float* __restrict__ src, f16* __restrict__ dst, int n)
{
    int idx = blockIdx.x*256 + threadIdx.x;
    if (idx < n) dst[idx] = (f16)src[idx];
}

// ======================= MFMA diffusion GEMM (R0 baseline, unchanged) =======================
__global__ __launch_bounds__(256)
void k_diff(const f16* __restrict__ Acv, const f16* __restrict__ Bt,
            f16* __restrict__ fout, int Mtot, int C, int G)
{
    __shared__ f16 lA[128*32];
    __shared__ f16 lB[128*32];
    const int tid = threadIdx.x;
    const int n0 = blockIdx.x*128, m0 = blockIdx.y*128;
    const int r0 = tid>>2, c0 = tid&3;
    const int swz0 = r0*32 + ((c0 ^ ((r0>>1)&3))<<3);
    const int swz1 = swz0 + 64*32;
    int mA0 = m0 + r0;      if (mA0 > Mtot-1) mA0 = Mtot-1;
    int mA1 = m0 + r0 + 64; if (mA1 > Mtot-1) mA1 = Mtot-1;
    const f16* gA0 = Acv + (size_t)mA0*512 + c0*8;
    const f16* gA1 = Acv + (size_t)mA1*512 + c0*8;
    const f16* gB0 = Bt + (size_t)(n0+r0)*512 + c0*8;
    const f16* gB1 = Bt + (size_t)(n0+r0+64)*512 + c0*8;

    const int w = tid>>6, lane = tid&63;
    const int wr = (w>>1)<<6, wc = (w&1)<<6;
    const int fm = lane&15, fk = lane>>4;
    const int fch = (fk ^ ((fm>>1)&3))<<3;

    f32x4 acc[4][4];
    #pragma unroll
    for (int i=0;i<4;i++)
        #pragma unroll
        for (int j=0;j<4;j++) acc[i][j] = (f32x4){0.f,0.f,0.f,0.f};

    f32x4 ra0 = *(const f32x4*)gA0, ra1 = *(const f32x4*)gA1;
    f32x4 rb0 = *(const f32x4*)gB0, rb1 = *(const f32x4*)gB1;

    for (int ks = 0; ks < 16; ks++) {
        __syncthreads();
        *(f32x4*)(lA + swz0) = ra0;  *(f32x4*)(lA + swz1) = ra1;
        *(f32x4*)(lB + swz0) = rb0;  *(f32x4*)(lB + swz1) = rb1;
        if (ks < 15) {
            int o = (ks+1)*32;
            ra0 = *(const f32x4*)(gA0 + o); ra1 = *(const f32x4*)(gA1 + o);
            rb0 = *(const f32x4*)(gB0 + o); rb1 = *(const f32x4*)(gB1 + o);
        }
        __syncthreads();
        f16x8 af[4], bf[4];
        #pragma unroll
        for (int i=0;i<4;i++) af[i] = *(const f16x8*)(lA + (wr + i*16 + fm)*32 + fch);
        #pragma unroll
        for (int j=0;j<4;j++) bf[j] = *(const f16x8*)(lB + (wc + j*16 + fm)*32 + fch);
        #pragma unroll
        for (int i=0;i<4;i++)
            #pragma unroll
            for (int j=0;j<4;j++)
                acc[i][j] = __builtin_amdgcn_mfma_f32_16x16x32_f16(af[i], bf[j], acc[i][j], 0, 0, 0);
    }

    #pragma unroll
    for (int j=0;j<4;j++) {
        int col = n0 + wc + j*16 + fm;
        int jb = col >> 9, wv = col & 511;
        if (wv >= 500) continue;
        #pragma unroll
        for (int i=0;i<4;i++) {
            int mb = m0 + wr + i*16 + fk*4;
            if (C == 64) {
                if (mb >= Mtot) continue;
                int b = mb >> 6, c = mb & 63;
                f16x4 h4;
                h4[0]=(f16)acc[i][j][0]; h4[1]=(f16)acc[i][j][1];
                h4[2]=(f16)acc[i][j][2]; h4[3]=(f16)acc[i][j][3];
                *(f16x4*)(fout + ((size_t)b*512 + wv)*G + C + jb*C + c) = h4;
            } else {
                #pragma unroll
                for (int r=0;r<4;r++) {
                    int m = mb + r;
                    if (m < Mtot) {
                        int b = m / C, c = m - b*C;
                        fout[((size_t)b*512 + wv)*G + C + jb*C + c] = (f16)acc[i][j][r];
                    }
                }
            }
        }
    }
}

// ======================= MFMA gates GEMM (R0 shape; f16 output) =======================
__global__ __launch_bounds__(256)
void k_gates(const f16* __restrict__ fT, const f16* __restrict__ Wg,
             const float* __restrict__ bg, f16* __restrict__ gT)
{
    __shared__ f16 lA[128*32];
    __shared__ f16 lB[128*32];
    const int tid = threadIdx.x;
    const int n0 = blockIdx.x*128, m0 = blockIdx.y*128, b = blockIdx.z;
    const f16* Ab = fT + (size_t)b*512*448;
    const int r0 = tid>>2, c0 = tid&3;
    const int swz0 = r0*32 + ((c0 ^ ((r0>>1)&3))<<3);
    const int swz1 = swz0 + 64*32;
    const f16* gA0 = Ab + (size_t)(m0+r0)*448 + c0*8;
    const f16* gA1 = Ab + (size_t)(m0+r0+64)*448 + c0*8;
    const f16* gB0 = Wg + (size_t)(n0+r0)*448 + c0*8;
    const f16* gB1 = Wg + (size_t)(n0+r0+64)*448 + c0*8;

    const int w = tid>>6, lane = tid&63;
    const int wr = (w>>1)<<6, wc = (w&1)<<6;
    const int fm = lane&15, fk = lane>>4;
    const int fch = (fk ^ ((fm>>1)&3))<<3;

    f32x4 acc[4][4];
    #pragma unroll
    for (int i=0;i<4;i++)
        #pragma unroll
        for (int j=0;j<4;j++) acc[i][j] = (f32x4){0.f,0.f,0.f,0.f};

    f32x4 ra0 = *(const f32x4*)gA0, ra1 = *(const f32x4*)gA1;
    f32x4 rb0 = *(const f32x4*)gB0, rb1 = *(const f32x4*)gB1;

    for (int ks = 0; ks < 14; ks++) {
        __syncthreads();
        *(f32x4*)(lA + swz0) = ra0;  *(f32x4*)(lA + swz1) = ra1;
        *(f32x4*)(lB + swz0) = rb0;  *(f32x4*)(lB + swz1) = rb1;
        if (ks < 13) {
            int o = (ks+1)*32;
            ra0 = *(const f32x4*)(gA0 + o); ra1 = *(const f32x4*)(gA1 + o);
            rb0 = *(const f32x4*)(gB0 + o); rb1 = *(const f32x4*)(gB1 + o);
        }
        __syncthreads();
        f16x8 af[4], bf[4];
        #pragma unroll
        for (int i=0;i<4;i++) af[i] = *(const f16x8*)(lA + (wr + i*16 + fm)*32 + fch);
        #pragma unroll
        for (int j=0;j<4;j++) bf[j] = *(const f16x8*)(lB + (wc + j*16 + fm)*32 + fch);
        #pragma unroll
        for (int i=0;i<4;i++)
            #pragma unroll
            for (int j=0;j<4;j++)
                acc[i][j] = __builtin_amdgcn_mfma_f32_16x16x32_f16(af[i], bf[j], acc[i][j], 0, 0, 0);
    }

    #pragma unroll
    for (int j=0;j<4;j++) {
        int o = n0 + wc + j*16 + fm;
        float bias = bg[o];
        #pragma unroll
        for (int i=0;i<4;i++) {
            int vb = m0 + wr + i*16 + fk*4;
            #pragma unroll
            for (int r=0;r<4;r++) {
                int v = vb + r;
                if (v < 500)
                    gT[((size_t)b*512 + v)*256 + o] = (f16)(acc[i][j][r] + bias);
            }
        }
    }
}

// ======================= comb (R0 structure; WoS padded to odd stride) =======================
__global__ __launch_bounds__(256)
void k_comb(const void* __restrict__ src, int srcF16, int Cin,
            const float* __restrict__ Wo, const float* __restrict__ bo,
            const float* __restrict__ se, const f16* __restrict__ hprev,
            f16* __restrict__ fT, f16* __restrict__ ccv)
{
    __shared__ float WoS[64*65];     // odd stride PS = Cin|1 kills 4-way bank conflicts
    __shared__ float seS[64], boS[64];
    __shared__ f16 combS[64*72];
    int b = blockIdx.y, v0 = blockIdx.x*64;
    int tid = threadIdx.x;
    const int PS = Cin | 1;
    if (Cin > 0) {
        for (int i = tid; i < 64*Cin; i += 256) {
            int r = i / Cin, cc = i - r*Cin;
            WoS[r*PS + cc] = Wo[i];
        }
        if (tid < 64) { boS[tid] = bo[tid]; seS[tid] = se ? se[b*64+tid] : 1.f; }
    }
    __syncthreads();
    int vloc = tid>>2, part = tid&3;
    int v = v0 + vloc;
    float val[16];
    if (Cin == 0) {
        const float* x3 = (const float*)src + ((size_t)b*512 + v)*64 + part*16;
        #pragma unroll
        for (int k=0;k<16;k++) val[k] = x3[k];
    } else {
        float acc[16];
        #pragma unroll
        for (int k=0;k<16;k++) acc[k] = 0.f;
        if (srcF16) {
            const f16* sp = (const f16*)src + ((size_t)b*512 + v)*64;
            for (int cc=0; cc<Cin; cc++) {
                float xv = (float)sp[cc];
                #pragma unroll
                for (int k=0;k<16;k++) acc[k] += WoS[(part*16+k)*PS + cc]*xv;
            }
        } else {
            const float* sp = (const float*)src + ((size_t)b*512 + v)*(size_t)Cin;
            for (int cc=0; cc<Cin; cc++) {
                float xv = sp[cc];
                #pragma unroll
                for (int k=0;k<16;k++) acc[k] += WoS[(part*16+k)*PS + cc]*xv;
            }
        }
        #pragma unroll
        for (int k=0;k<16;k++) { int c = part*16+k; val[k] = seS[c]*(acc[k] + boS[c]); }
    }
    if (hprev) {
        const f16* hp = hprev + ((size_t)b*512 + v)*64 + part*16;
        #pragma unroll
        for (int k=0;k<16;k++) val[k] += (float)hp[k];
    }
    if (v >= 500) {
        #pragma unroll
        for (int k=0;k<16;k++) val[k] = 0.f;
    }
    #pragma unroll
    for (int k=0;k<16;k++) combS[vloc*72 + part*16 + k] = (f16)val[k];
    __syncthreads();
    {
        int vl = tid>>2, p = tid&3;
        f32x4 d0 = *(f32x4*)(combS + vl*72 + p*16);
        f32x4 d1 = *(f32x4*)(combS + vl*72 + p*16 + 8);
        f16* dst = fT + ((size_t)b*512 + (v0+vl))*448 + p*16;
        *(f32x4*)dst = d0; *(f32x4*)(dst+8) = d1;
    }
    {
        int c = tid>>2, p = tid&3;
        alignas(16) f16 tmp[16];
        #pragma unroll
        for (int k=0;k<16;k++) tmp[k] = combS[(p*16+k)*72 + c];
        f16* dst = ccv + ((size_t)b*64 + c)*512 + v0 + p*16;
        *(f32x4*)dst = *(f32x4*)tmp; *(f32x4*)(dst+8) = *(f32x4*)(tmp+8);
    }
}

// ======================= LSTM pointwise (layers 1,2) — f16 gates =======================
__global__ void k_lstm(const f16* __restrict__ gT, float* __restrict__ cst,
                       f16* __restrict__ hdst, int first)
{
    int id = blockIdx.x*4 + (threadIdx.x>>6);
    if (id >= NB*500) return;
    int b = id / 500, v = id - b*500;
    int c = threadIdx.x & 63;
    const f16* g = gT + ((size_t)b*512 + v)*256;
    float gi = (float)g[c], gf = (float)g[64+c], gc = (float)g[128+c], go = (float)g[192+c];
    size_t ci = ((size_t)b*512 + v)*64 + c;
    float cx = first ? 0.f : cst[ci];
    float cy = sigm(gf)*cx + sigm(gi)*gc;
    cst[ci] = cy;
    hdst[ci] = (f16)(sigm(go)*tanhf(cy));
}

// ======================= LSTM + output projection (layer 3) — f16 gates =======================
__global__ void k_lstm3out(const f16* __restrict__ gT, float* __restrict__ cst,
                           f16* __restrict__ hdst, const float* __restrict__ Wo3,
                           const float* __restrict__ bo3, float* __restrict__ out,
                           int t, int first)
{
    int id = blockIdx.x*4 + (threadIdx.x>>6);
    if (id >= NB*500) return;
    int b = id / 500, v = id - b*500;
    int c = threadIdx.x & 63;
    const f16* g = gT + ((size_t)b*512 + v)*256;
    float gi = (float)g[c], gf = (float)g[64+c], gc = (float)g[128+c], go = (float)g[192+c];
    size_t ci = ((size_t)b*512 + v)*64 + c;
    float cx = first ? 0.f : cst[ci];
    float cy = sigm(gf)*cx + sigm(gi)*gc;
    cst[ci] = cy;
    float hy = sigm(go)*tanhf(cy);
    hdst[ci] = (f16)hy;
    float r0 = Wo3[c]*hy, r1 = Wo3[64+c]*hy;
    #pragma unroll
    for (int s = 32; s > 0; s >>= 1) {
        r0 += __shfl_down(r0, s, 64);
        r1 += __shfl_down(r1, s, 64);
    }
    if (c == 0) {
        out[((size_t)(b*2+0)*500 + v)*24 + t] = r0 + bo3[0];
        out[((size_t)(b*2+1)*500 + v)*24 + t] = r1 + bo3[1];
    }
}

// ======================= layer 0 (hoisted XE + fused gates/lstm/comb; R3-verified) =======================
__global__ void k_xe(const float* __restrict__ x, const int* __restrict__ wt,
                     const float* __restrict__ Wemb, float* __restrict__ XE)
{
    int id = blockIdx.x*256 + threadIdx.x;
    if (id >= NT*NB*512) return;
    int v = id & 511; int r = id >> 9; int b = r & 31; int t = r >> 5;
    float vals[6] = {0.f,0.f,0.f,0.f,0.f,0.f};
    if (v < 500) {
        vals[0] = x[((size_t)(b*2+0)*500 + v)*24 + t];
        vals[1] = x[((size_t)(b*2+1)*500 + v)*24 + t];
        int wty = wt[((size_t)b*500 + v)*24 + t];
        vals[2] = Wemb[wty*4+0]; vals[3] = Wemb[wty*4+1];
        vals[4] = Wemb[wty*4+2]; vals[5] = Wemb[wty*4+3];
    }
    float* xe = XE + (size_t)id*6;
    #pragma unroll
    for (int c = 0; c < 6; c++) xe[c] = vals[c];
}

__global__ void k_seed0(const float* __restrict__ XE, f16* __restrict__ f0T,
                        f16* __restrict__ ccv0)
{
    int id = blockIdx.x*256 + threadIdx.x;
    if (id >= NB*512) return;
    int v = id & 511, b = id >> 9;
    const float* xe = XE + (size_t)id*6;
    #pragma unroll
    for (int c = 0; c < 6; c++) {
        f16 h = (v < 500) ? (f16)xe[c] : (f16)0.f;
        f0T[(size_t)id*42 + c] = h;
        ccv0[((size_t)b*6 + c)*512 + v] = h;
    }
}

__global__ __launch_bounds__(256)
void k_glstm0(f16* f0T, const float* __restrict__ Wg0,
              const float* __restrict__ bg0, float* __restrict__ cst0,
              float* __restrict__ hs0T, const float* __restrict__ XE,
              f16* __restrict__ ccv0, int t)
{
    __shared__ float WgS[24*42];
    __shared__ float bgS[24];
    int tid = threadIdx.x;
    for (int i = tid; i < 24*42; i += 256) WgS[i] = Wg0[i];
    if (tid < 24) bgS[tid] = bg0[tid];
    __syncthreads();
    int id = blockIdx.x*256 + tid;
    if (id >= NB*500) return;
    int b = id / 500, v = id - b*500;
    const f16* fp = f0T + ((size_t)b*512 + v)*42;
    float fv[42];
    #pragma unroll
    for (int g = 0; g < 42; g++) fv[g] = (float)fp[g];
    float gates[24];
    #pragma unroll
    for (int o = 0; o < 24; o++) {
        float a = bgS[o];
        #pragma unroll
        for (int g = 0; g < 42; g++) a += WgS[o*42+g]*fv[g];
        gates[o] = a;
    }
    size_t hrow = (((size_t)t*NB + b)*512 + v)*6;
    const float* xe = XE + (((size_t)(t+1)*NB + b)*512 + v)*6;   // only read if t<23
    #pragma unroll
    for (int c = 0; c < 6; c++) {
        size_t ci = ((size_t)b*500 + v)*6 + c;
        float cx = t ? cst0[ci] : 0.f;
        float cy = sigm(gates[6+c])*cx + sigm(gates[c])*gates[12+c];
        cst0[ci] = cy;
        float h = sigm(gates[18+c])*tanhf(cy);
        hs0T[hrow + c] = h;
        if (t < 23) {
            float cmb = xe[c] + h;
            f0T[((size_t)b*512 + v)*42 + c] = (f16)cmb;
            ccv0[((size_t)b*6 + c)*512 + v] = (f16)cmb;
        }
    }
}

// ======================= SE path (R0 unchanged) =======================
__global__ void k_mean0(const float* __restrict__ hs0T, float* __restrict__ mean0)
{
    int b = blockIdx.x;
    float acc[6] = {0,0,0,0,0,0};
    for (int i = threadIdx.x; i < 24*500; i += 256) {
        int tt = i/500, v = i - tt*500;
        const float* p = hs0T + (((size_t)tt*NB + b)*512 + v)*6;
        #pragma unroll
        for (int c=0;c<6;c++) acc[c] += p[c];
    }
    __shared__ float red[256];
    for (int c=0;c<6;c++) {
        red[threadIdx.x] = acc[c]; __syncthreads();
        for (int s=128;s>0;s>>=1) { if (threadIdx.x<s) red[threadIdx.x]+=red[threadIdx.x+s]; __syncthreads(); }
        if (threadIdx.x==0) mean0[b*6+c] = red[0]/12000.f;
        __syncthreads();
    }
}

__global__ void k_mean1(const f16* __restrict__ hs1T, float* __restrict__ mean1)
{
    int cg = blockIdx.x, b = blockIdx.y;
    float acc[8] = {0,0,0,0,0,0,0,0};
    for (int i = threadIdx.x; i < 24*500; i += 256) {
        int tt = i/500, v = i - tt*500;
        const f16* p = hs1T + (((size_t)tt*NB + b)*512 + v)*64 + cg*8;
        #pragma unroll
        for (int c=0;c<8;c++) acc[c] += (float)p[c];
    }
    __shared__ float red[256];
    for (int c=0;c<8;c++) {
        red[threadIdx.x] = acc[c]; __syncthreads();
        for (int s=128;s>0;s>>=1) { if (threadIdx.x<s) red[threadIdx.x]+=red[threadIdx.x+s]; __syncthreads(); }
        if (threadIdx.x==0) mean1[b*64 + cg*8 + c] = red[0]/12000.f;
        __syncthreads();
    }
}

__global__ void k_se(const float* __restrict__ meanhs, const float* __restrict__ Wo,
                     const float* __restrict__ bo, int Cin,
                     const float* __restrict__ Wa, const float* __restrict__ Wb,
                     float* __restrict__ se)
{
    int b = blockIdx.x; int c = threadIdx.x;
    __shared__ float y[64]; __shared__ float a[4];
    float acc = bo[c];
    for (int j = 0; j < Cin; j++) acc += Wo[(size_t)c*Cin + j] * meanhs[b*Cin + j];
    y[c] = acc;
    __syncthreads();
    if (c < 4) {
        float s = 0.f;
        for (int j = 0; j < 64; j++) s += Wa[c*64 + j] * y[j];
        a[c] = fmaxf(s, 0.f);
    }
    __syncthreads();
    float s = 0.f;
    #pragma unroll
    for (int j = 0; j < 4; j++) s += Wb[c*4 + j] * a[j];
    se[b*64 + c] = 1.f/(1.f + expf(-s));
}

// ======================= x3 = Wo2 @ h2_last + bo2 (R0 unchanged) =======================
__global__ void k_x3(const f16* __restrict__ h, const float* __restrict__ Wo,
                     const float* __restrict__ bo, float* __restrict__ x3T)
{
    int idx = blockIdx.x*256 + threadIdx.x;
    if (idx >= NB*500*64) return;
    int c = idx & 63; int rest = idx >> 6; int v = rest % 500; int b = rest/500;
    const f16* hp = h + ((size_t)b*512 + v)*64;
    float a = bo[c];
    #pragma unroll 8
    for (int cc = 0; cc < 64; cc++) a += Wo[c*64 + cc]*(float)hp[cc];
    x3T[((size_t)b*512 + v)*64 + c] = a;
}

// ======================= host launch =======================
extern "C" void kernel_launch(void* const* d_in, const int* in_sizes, int n_in,
                              void* d_out, int out_size, void* d_ws, size_t ws_size,
                              hipStream_t stream)
{
    const float* x    = (const float*)d_in[0];
    const float* sup  = (const float*)d_in[1];
    const int*   wt   = (const int*)  d_in[2];
    const float* Wemb = (const float*)d_in[3];
    const float* Wg0  = (const float*)d_in[4];
    const float* bg0  = (const float*)d_in[5];
    const float* Wo0  = (const float*)d_in[6];
    const float* bo0  = (const float*)d_in[7];
    const float* Wa0  = (const float*)d_in[8];
    const float* Wb0  = (const float*)d_in[9];
    const float* Wg1  = (const float*)d_in[10];
    const float* bg1  = (const float*)d_in[11];
    const float* Wo1  = (const float*)d_in[12];
    const float* bo1  = (const float*)d_in[13];
    const float* Wa1  = (const float*)d_in[14];
    const float* Wb1  = (const float*)d_in[15];
    const float* Wg2  = (const float*)d_in[16];
    const float* bg2  = (const float*)d_in[17];
    const float* Wo2  = (const float*)d_in[18];
    const float* bo2  = (const float*)d_in[19];
    const float* Wg3  = (const float*)d_in[20];
    const float* bg3  = (const float*)d_in[21];
    const float* Wo3  = (const float*)d_in[22];
    const float* bo3  = (const float*)d_in[23];
    float* out = (float*)d_out;
    (void)in_sizes; (void)n_in; (void)out_size; (void)ws_size;

    char* ws = (char*)d_ws;
    size_t off = 0;
    f16*   AcatT  = (f16*)(ws + off);   off += (size_t)3072*512*2;
    f16*   A16    = (f16*)(ws + off);   off += (size_t)3*512*512*2;
    f16*   WgF1   = (f16*)(ws + off);   off += (size_t)256*448*2;
    f16*   WgF2   = (f16*)(ws + off);   off += (size_t)256*448*2;
    f16*   WgF3   = (f16*)(ws + off);   off += (size_t)256*448*2;
    f16*   comb_cv= (f16*)(ws + off);   off += (size_t)2048*512*2;
    f16*   ccv0   = (f16*)(ws + off);   off += (size_t)192*512*2;
    f16*   featsT = (f16*)(ws + off);   off += (size_t)NB*512*448*2;
    f16*   f0T    = (f16*)(ws + off);   off += (size_t)NB*512*42*2;
    f16*   gatesT = (f16*)(ws + off);   off += (size_t)NB*512*256*2;
    float* XE     = (float*)(ws + off); off += (size_t)NT*NB*512*6*4;
    float* hs0T   = (float*)(ws + off); off += (size_t)NT*NB*512*6*4;
    f16*   hs1T   = (f16*)(ws + off);   off += (size_t)NT*NB*512*64*2;
    f16*   hT     = (f16*)(ws + off);   off += (size_t)NB*512*64*2;
    float* cstT   = (float*)(ws + off); off += (size_t)NB*512*64*4;
    float* cst0   = (float*)(ws + off); off += (size_t)NB*500*6*4;
    float* x3T    = (float*)(ws + off); off += (size_t)NB*512*64*4;
    float* mean0  = (float*)(ws + off); off += 8192;
    float* se0    = (float*)(ws + off); off += 8192;
    float* mean1  = (float*)(ws + off); off += 8192;
    float* se1    = (float*)(ws + off); off += 8192;

    const size_t sliceH = (size_t)NB*512*64;
    const size_t slice0 = (size_t)NB*512*6;

    // ---- prep ----
    k_prep_a<<<dim3(8, 8, 3), 256, 0, stream>>>(sup, AcatT, A16);
    k_a2m   <<<dim3(4, 4, 3), 256, 0, stream>>>(AcatT, A16);
    k_f2h <<<(256*448 + 255)/256, 256, 0, stream>>>(Wg1, WgF1, 256*448);
    k_f2h <<<(256*448 + 255)/256, 256, 0, stream>>>(Wg2, WgF2, 256*448);
    k_f2h <<<(256*448 + 255)/256, 256, 0, stream>>>(Wg3, WgF3, 256*448);
    k_xe  <<<(NT*NB*512)/256, 256, 0, stream>>>(x, wt, Wemb, XE);

    // ---- layer 0 ----
    k_seed0<<<(NB*512)/256, 256, 0, stream>>>(XE, f0T, ccv0);
    for (int t = 0; t < NT; t++) {
        k_diff  <<<dim3(24, 2), 256, 0, stream>>>(ccv0, AcatT, f0T, 192, 6, 42);
        k_glstm0<<<(NB*500 + 255)/256, 256, 0, stream>>>(f0T, Wg0, bg0, cst0, hs0T, XE, ccv0, t);
    }
    k_mean0<<<NB, 256, 0, stream>>>(hs0T, mean0);
    k_se   <<<NB, 64, 0, stream>>>(mean0, Wo0, bo0, 6, Wa0, Wb0, se0);

    // ---- layer 1 ----
    for (int t = 0; t < NT; t++) {
        k_comb <<<dim3(8, NB), 256, 0, stream>>>(hs0T + (size_t)t*slice0, 0, 6,
                 Wo0, bo0, se0, t ? hs1T + (size_t)(t-1)*sliceH : (const f16*)nullptr,
                 featsT, comb_cv);
        k_diff <<<dim3(24, 16), 256, 0, stream>>>(comb_cv, AcatT, featsT, 2048, 64, 448);
        k_gates<<<dim3(2, 4, NB), 256, 0, stream>>>(featsT, WgF1, bg1, gatesT);
        k_lstm <<<4000, 256, 0, stream>>>(gatesT, cstT, hs1T + (size_t)t*sliceH, t == 0);
    }
    k_mean1<<<dim3(8, NB), 256, 0, stream>>>(hs1T, mean1);
    k_se   <<<NB, 64, 0, stream>>>(mean1, Wo1, bo1, 64, Wa1, Wb1, se1);

    // ---- layer 2 ----
    for (int t = 0; t < NT; t++) {
        k_comb <<<dim3(8, NB), 256, 0, stream>>>(hs1T + (size_t)t*sliceH, 1, 64,
                 Wo1, bo1, se1, t ? hT : (const f16*)nullptr, featsT, comb_cv);
        k_diff <<<dim3(24, 16), 256, 0, stream>>>(comb_cv, AcatT, featsT, 2048, 64, 448);
        k_gates<<<dim3(2, 4, NB), 256, 0, stream>>>(featsT, WgF2, bg2, gatesT);
        k_lstm <<<4000, 256, 0, stream>>>(gatesT, cstT, hT, t == 0);
    }
    k_x3<<<(NB*500*64 + 255)/256, 256, 0, stream>>>(hT, Wo2, bo2, x3T);

    // ---- layer 3 ----
    for (int t = 0; t < NT; t++) {
        k_comb <<<dim3(8, NB), 256, 0, stream>>>(x3T, 0, 0,
                 (const float*)nullptr, (const float*)nullptr, (const float*)nullptr,
                 t ? hT : (const f16*)nullptr, featsT, comb_cv);
        k_diff <<<dim3(24, 16), 256, 0, stream>>>(comb_cv, AcatT, featsT, 2048, 64, 448);
        k_gates<<<dim3(2, 4, NB), 256, 0, stream>>>(featsT, WgF3, bg3, gatesT);
        k_lstm3out<<<4000, 256, 0, stream>>>(gatesT, cstT, hT, Wo3, bo3, out, t, t == 0);
    }
}